// Round 1
// baseline (7849.971 us; speedup 1.0000x reference)
//
#include <hip/hip_runtime.h>
#include <math.h>

#define NPROTO 8

// ---------------- prototype projection / argmax-class kernel ----------------
// one wave (64 lanes) per token; 4 waves per block; covers feat0 then feat1
__global__ __launch_bounds__(256) void lft_class_kernel(
    const float* __restrict__ f0wo, const float* __restrict__ f1wo,
    const int* __restrict__ mask0, const int* __restrict__ mask1,
    const float* __restrict__ proto,
    float* out, int* cls0, int* cls1)
{
    __shared__ float pr[2048];
    int t = threadIdx.x;
    *(float4*)&pr[t * 4]        = *(const float4*)&proto[t * 4];
    *(float4*)&pr[1024 + t * 4] = *(const float4*)&proto[1024 + t * 4];
    __syncthreads();
    int wave = t >> 6, lane = t & 63;
    long token = (long)blockIdx.x * 4 + wave;
    const float* fsrc; const int* msrc; float* fpout; float* clsout; int* clsarr; long tok;
    if (token < 38400) {
        tok = token; fsrc = f0wo; msrc = mask0;
        fpout = out + 19737600L; clsout = out + 19660800L; clsarr = cls0;
    } else {
        tok = token - 38400; fsrc = f1wo; msrc = mask1;
        fpout = out + 20044800L; clsout = out + 19699200L; clsarr = cls1;
    }
    float4 f = *(const float4*)&fsrc[tok * 256 + lane * 4];
    float s[NPROTO];
#pragma unroll
    for (int p = 0; p < NPROTO; p++) {
        float4 pv = *(const float4*)&pr[p * 256 + lane * 4];
        float d = f.x * pv.x + f.y * pv.y + f.z * pv.z + f.w * pv.w;
#pragma unroll
        for (int o = 32; o >= 1; o >>= 1) d += __shfl_xor(d, o, 64);
        s[p] = d;
    }
    if (lane == 0) {
        int best = 0; float bv = s[0];
#pragma unroll
        for (int p = 1; p < NPROTO; p++) { if (s[p] > bv) { bv = s[p]; best = p; } }
#pragma unroll
        for (int p = 0; p < NPROTO; p++) fpout[tok * 8 + p] = s[p];
        clsout[tok] = (float)best;
        clsarr[tok] = msrc[tok] ? best : -1;
    }
}

// ---------------- fp32 tiled GEMM: C[38400,N] = act( [A0|A1][38400,K] @ W[K,N] ) ----
// BM=128, BN=64, BK=16; 256 threads; each thread 8x4 outputs.
// act: 0=none, 1=phi(z)=elu(z)+1, 2=relu
__global__ __launch_bounds__(256) void lft_gemm_kernel(
    const float* __restrict__ A0, const float* __restrict__ A1, int kSplit,
    const float* __restrict__ W, float* C, int N, int K, int act)
{
    __shared__ float As[16][132];
    __shared__ float Bs[16][64];
    int t = threadIdx.x;
    int m0 = blockIdx.y << 7;
    int n0 = blockIdx.x << 6;
    int tm = t >> 4, tn = t & 15;
    float acc[8][4] = {{0.f}};
    for (int k0 = 0; k0 < K; k0 += 16) {
        const float* Asrc = (k0 < kSplit) ? A0 : A1;
        int ldA  = (k0 < kSplit) ? kSplit : (K - kSplit);
        int kcol = (k0 < kSplit) ? k0 : (k0 - kSplit);
#pragma unroll
        for (int rep = 0; rep < 2; rep++) {
            int f = t + (rep << 8);
            int row = f >> 2;
            int kc = (f & 3) << 2;
            float4 av = *(const float4*)&Asrc[(size_t)(m0 + row) * ldA + kcol + kc];
            As[kc + 0][row] = av.x;
            As[kc + 1][row] = av.y;
            As[kc + 2][row] = av.z;
            As[kc + 3][row] = av.w;
        }
        {
            int krow = t >> 4, nc = (t & 15) << 2;
            *(float4*)&Bs[krow][nc] = *(const float4*)&W[(size_t)(k0 + krow) * N + n0 + nc];
        }
        __syncthreads();
#pragma unroll
        for (int kk = 0; kk < 16; kk++) {
            float a8[8], b4[4];
            *(float4*)&a8[0] = *(const float4*)&As[kk][tm * 8];
            *(float4*)&a8[4] = *(const float4*)&As[kk][tm * 8 + 4];
            *(float4*)&b4[0] = *(const float4*)&Bs[kk][tn << 2];
#pragma unroll
            for (int i = 0; i < 8; i++)
#pragma unroll
                for (int j = 0; j < 4; j++)
                    acc[i][j] += a8[i] * b4[j];
        }
        __syncthreads();
    }
#pragma unroll
    for (int i = 0; i < 8; i++) {
        long row = m0 + tm * 8 + i;
        float o[4];
#pragma unroll
        for (int j = 0; j < 4; j++) {
            float fv = acc[i][j];
            if (act == 1)      fv = fv > 0.f ? fv + 1.f : expf(fv);
            else if (act == 2) fv = fmaxf(fv, 0.f);
            o[j] = fv;
        }
        *(float4*)&C[row * N + n0 + (tn << 2)] = *(float4*)&o[0];
    }
}

// ---------------- per-class KV / Ksum reduction ----------------
// grid (chunk=8, h=8, b=8); block 256; thread owns (d = t>>3, e = (t&7)*4..+3)
// accumulators per class in registers (predicated), atomicAdd to global.
__global__ __launch_bounds__(256) void lft_kv_kernel(
    const float* __restrict__ phik, const float* __restrict__ vmat,
    const int* __restrict__ cls, float* kv, float* ksum)
{
    int chunk = blockIdx.x, h = blockIdx.y, b = blockIdx.z;
    int t = threadIdx.x;
    const int CH = 600;
    int s0 = chunk * CH;
    __shared__ float kb[8][32];
    __shared__ float vb[8][32];
    __shared__ int cb[8];
    int od = t >> 3;
    int oe = (t & 7) << 2;
    int lt = t >> 5, ld = t & 31;
    float acc[NPROTO][4] = {{0.f}};
    float ak[NPROTO] = {0.f};
    for (int s = s0; s < s0 + CH; s += 8) {
        long base = ((long)b * 4800 + s + lt) * 256 + h * 32 + ld;
        float kval = phik[base];
        float vval = vmat[base];
        int cv = (t < 8) ? cls[b * 4800 + s + t] : 0;
        __syncthreads();
        kb[lt][ld] = kval;
        vb[lt][ld] = vval;
        if (t < 8) cb[t] = cv;
        __syncthreads();
#pragma unroll
        for (int j = 0; j < 8; j++) {
            int c = cb[j];
            float kd = kb[j][od];
            float4 vv = *(const float4*)&vb[j][oe];
#pragma unroll
            for (int cc = 0; cc < NPROTO; cc++) {
                float kdm = (c == cc) ? kd : 0.f;
                acc[cc][0] += kdm * vv.x;
                acc[cc][1] += kdm * vv.y;
                acc[cc][2] += kdm * vv.z;
                acc[cc][3] += kdm * vv.w;
                ak[cc] += kdm;
            }
        }
    }
#pragma unroll
    for (int cc = 0; cc < NPROTO; cc++) {
        float* dst = kv + (((long)(b * NPROTO + cc) * 8 + h) << 10) + od * 32 + oe;
        atomicAdd(dst + 0, acc[cc][0]);
        atomicAdd(dst + 1, acc[cc][1]);
        atomicAdd(dst + 2, acc[cc][2]);
        atomicAdd(dst + 3, acc[cc][3]);
        if ((t & 7) == 0)
            atomicAdd(ksum + (((long)(b * NPROTO + cc) * 8 + h) << 5) + od, ak[cc]);
    }
}

// ---------------- msg = (phi_q . kv[c]) / (phi_q . ksum[c] + eps) ----------------
// one block per token; thread t -> (h = t>>5, e = t&31)
__global__ __launch_bounds__(256) void lft_msg_kernel(
    const float* __restrict__ phiq, const float* __restrict__ kv,
    const float* __restrict__ ksum, const int* __restrict__ cls,
    float* msg)
{
    long token = blockIdx.x;
    int t = threadIdx.x;
    int c = cls[token];
    if (c < 0) { msg[token * 256 + t] = 0.f; return; }
    int b = (int)(token / 4800);
    __shared__ float pq[256];
    pq[t] = phiq[token * 256 + t];
    __syncthreads();
    int h = t >> 5, e = t & 31;
    const float* kvp = kv + (((long)(b * NPROTO + c) * 8 + h) << 10) + e;
    const float* ksp = ksum + (((long)(b * NPROTO + c) * 8 + h) << 5);
    const float* pqh = pq + h * 32;
    float num = 0.f, den = 0.f;
#pragma unroll
    for (int d = 0; d < 32; d++) {
        float p = pqh[d];
        num += p * kvp[d * 32];
        den += p * ksp[d];
    }
    msg[token * 256 + t] = num / (den + 1e-6f);
}

// ---------------- row LayerNorm (256) , optional residual+mask ----------------
// out = resid ? (valid ? resid + LN(in)*g+b : resid) : LN(in)*g+b
__global__ __launch_bounds__(256) void lft_ln_kernel(
    const float* __restrict__ in, float* out,
    const float* __restrict__ g, const float* __restrict__ bb,
    const float* resid, const int* __restrict__ cls)
{
    int wave = threadIdx.x >> 6, lane = threadIdx.x & 63;
    long row = (long)blockIdx.x * 4 + wave;
    float4 x = *(const float4*)&in[row * 256 + lane * 4];
    float s = x.x + x.y + x.z + x.w;
#pragma unroll
    for (int o = 32; o >= 1; o >>= 1) s += __shfl_xor(s, o, 64);
    float mean = s * (1.0f / 256.0f);
    float dx = x.x - mean, dy = x.y - mean, dz = x.z - mean, dw = x.w - mean;
    float vs = dx * dx + dy * dy + dz * dz + dw * dw;
#pragma unroll
    for (int o = 32; o >= 1; o >>= 1) vs += __shfl_xor(vs, o, 64);
    float r = rsqrtf(vs * (1.0f / 256.0f) + 1e-5f);
    float4 gv = *(const float4*)&g[lane * 4];
    float4 bv = *(const float4*)&bb[lane * 4];
    float4 y;
    y.x = dx * r * gv.x + bv.x;
    y.y = dy * r * gv.y + bv.y;
    y.z = dz * r * gv.z + bv.z;
    y.w = dw * r * gv.w + bv.w;
    if (resid) {
        float4 xr = *(const float4*)&resid[row * 256 + lane * 4];
        if (cls[row] >= 0) { y.x += xr.x; y.y += xr.y; y.z += xr.z; y.w += xr.w; }
        else y = xr;
    }
    *(float4*)&out[row * 256 + lane * 4] = y;
}

extern "C" void kernel_launch(void* const* d_in, const int* in_sizes, int n_in,
                              void* d_out, int out_size, void* d_ws, size_t ws_size,
                              hipStream_t stream)
{
    (void)in_sizes; (void)n_in; (void)out_size; (void)ws_size;
    const float* feat0 = (const float*)d_in[0];
    const float* feat1 = (const float*)d_in[1];
    const int*   mask0 = (const int*)d_in[2];
    const int*   mask1 = (const int*)d_in[3];
    const float* f0wo  = (const float*)d_in[4];
    const float* f1wo  = (const float*)d_in[5];
    const float* proto = (const float*)d_in[6];
    const float* Wq = (const float*)d_in[7];
    const float* Wk = (const float*)d_in[8];
    const float* Wv = (const float*)d_in[9];
    const float* Wm = (const float*)d_in[10];
    const float* W1 = (const float*)d_in[11];
    const float* W2 = (const float*)d_in[12];
    const float* g1 = (const float*)d_in[13];
    const float* b1 = (const float*)d_in[14];
    const float* g2 = (const float*)d_in[15];
    const float* b2 = (const float*)d_in[16];
    float* out = (float*)d_out;
    float* ws = (float*)d_ws;

    const long FSZ = 9830400L;           // 8*4800*256
    float* fa   = ws;                    // current feat0
    float* fb   = ws + FSZ;              // current feat1
    float* qb   = ws + 2 * FSZ;          // phi_q / W2-output scratch
    float* msgb = ws + 3 * FSZ;          // msg / LN(msg@Wm)
    float* hid  = ws + 4 * FSZ;          // 2*FSZ: k/v staging, then Wm out, then W1 out
    float* kvb  = ws + 6 * FSZ;          // [B,NP,H,D,D] = 524288
    float* ksb  = kvb + 524288;          // [B,NP,H,D]   = 16384
    int* cls0 = (int*)(ksb + 16384);     // 38400 ints (-1 = invalid)
    int* cls1 = cls0 + 38400;
    float* kbuf = hid;
    float* vbuf = hid + FSZ;

    hipMemcpyAsync(fa, feat0, FSZ * 4, hipMemcpyDeviceToDevice, stream);
    hipMemcpyAsync(fb, feat1, FSZ * 4, hipMemcpyDeviceToDevice, stream);
    hipMemcpyAsync(out + 20352000L, proto, 2048 * 4, hipMemcpyDeviceToDevice, stream);
    lft_class_kernel<<<19200, 256, 0, stream>>>(f0wo, f1wo, mask0, mask1, proto,
                                                out, cls0, cls1);

    for (int li = 0; li < 4; li++) {
        const float* wq = Wq + (size_t)li * 65536;
        const float* wk = Wk + (size_t)li * 65536;
        const float* wv = Wv + (size_t)li * 65536;
        const float* wm = Wm + (size_t)li * 65536;
        const float* w1 = W1 + (size_t)li * 262144;
        const float* w2 = W2 + (size_t)li * 131072;
        const float* g1p = g1 + li * 256; const float* b1p = b1 + li * 256;
        const float* g2p = g2 + li * 256; const float* b2p = b2 + li * 256;

        auto call = [&](float* x, float* src, const int* clsx, const int* clssrc) {
            dim3 blk(256);
            dim3 gA(4, 300), gB(8, 300);
            // q = phi(x@Wq), k = phi(src@Wk), v = src@Wv
            lft_gemm_kernel<<<gA, blk, 0, stream>>>(x, x, 256, wq, qb, 256, 256, 1);
            lft_gemm_kernel<<<gA, blk, 0, stream>>>(src, src, 256, wk, kbuf, 256, 256, 1);
            lft_gemm_kernel<<<gA, blk, 0, stream>>>(src, src, 256, wv, vbuf, 256, 256, 0);
            hipMemsetAsync(kvb, 0, (524288 + 16384) * 4, stream);
            lft_kv_kernel<<<dim3(8, 8, 8), blk, 0, stream>>>(kbuf, vbuf, clssrc, kvb, ksb);
            lft_msg_kernel<<<38400, blk, 0, stream>>>(qb, kvb, ksb, clsx, msgb);
            // msg = LN(msg @ Wm)*g1+b1
            lft_gemm_kernel<<<gA, blk, 0, stream>>>(msgb, msgb, 256, wm, hid, 256, 256, 0);
            lft_ln_kernel<<<9600, blk, 0, stream>>>(hid, msgb, g1p, b1p, nullptr, nullptr);
            // hid = relu([x|msg]@W1) ; m = hid@W2 ; x = valid ? x + LN(m)*g2+b2 : x
            lft_gemm_kernel<<<gB, blk, 0, stream>>>(x, msgb, 256, w1, hid, 512, 512, 2);
            lft_gemm_kernel<<<gA, blk, 0, stream>>>(hid, hid, 512, w2, qb, 256, 512, 0);
            lft_ln_kernel<<<9600, blk, 0, stream>>>(qb, x, g2p, b2p, x, clsx);
        };

        if ((li & 1) == 0) {           // self-self
            call(fa, fa, cls0, cls0);
            call(fb, fb, cls1, cls1);
        } else {                       // cross-self: new0 first, then feat1 vs updated feat0
            call(fa, fb, cls0, cls1);
            call(fb, fa, cls1, cls0);
        }
    }
    hipMemcpyAsync(out,       fa, FSZ * 4, hipMemcpyDeviceToDevice, stream);
    hipMemcpyAsync(out + FSZ, fb, FSZ * 4, hipMemcpyDeviceToDevice, stream);
}

// Round 2
// 3499.081 us; speedup vs baseline: 2.2434x; 2.2434x over previous
//
#include <hip/hip_runtime.h>
#include <math.h>

#define NPROTO 8

typedef __attribute__((ext_vector_type(8))) short short8;
typedef __attribute__((ext_vector_type(4))) float floatx4;

static __device__ __forceinline__ ushort f2b(float f) {
    unsigned u = __builtin_bit_cast(unsigned, f);
    unsigned r = (u + 0x7fffu + ((u >> 16) & 1u)) >> 16;
    return (ushort)r;
}

// ---------------- prototype projection / argmax-class kernel ----------------
__global__ __launch_bounds__(256) void lft_class_kernel(
    const float* __restrict__ f0wo, const float* __restrict__ f1wo,
    const int* __restrict__ mask0, const int* __restrict__ mask1,
    const float* __restrict__ proto,
    float* out, int* cls0, int* cls1)
{
    __shared__ float pr[2048];
    int t = threadIdx.x;
    *(float4*)&pr[t * 4]        = *(const float4*)&proto[t * 4];
    *(float4*)&pr[1024 + t * 4] = *(const float4*)&proto[1024 + t * 4];
    __syncthreads();
    int wave = t >> 6, lane = t & 63;
    long token = (long)blockIdx.x * 4 + wave;
    const float* fsrc; const int* msrc; float* fpout; float* clsout; int* clsarr; long tok;
    if (token < 38400) {
        tok = token; fsrc = f0wo; msrc = mask0;
        fpout = out + 19737600L; clsout = out + 19660800L; clsarr = cls0;
    } else {
        tok = token - 38400; fsrc = f1wo; msrc = mask1;
        fpout = out + 20044800L; clsout = out + 19699200L; clsarr = cls1;
    }
    float4 f = *(const float4*)&fsrc[tok * 256 + lane * 4];
    float s[NPROTO];
#pragma unroll
    for (int p = 0; p < NPROTO; p++) {
        float4 pv = *(const float4*)&pr[p * 256 + lane * 4];
        float d = f.x * pv.x + f.y * pv.y + f.z * pv.z + f.w * pv.w;
#pragma unroll
        for (int o = 32; o >= 1; o >>= 1) d += __shfl_xor(d, o, 64);
        s[p] = d;
    }
    if (lane == 0) {
        int best = 0; float bv = s[0];
#pragma unroll
        for (int p = 1; p < NPROTO; p++) { if (s[p] > bv) { bv = s[p]; best = p; } }
#pragma unroll
        for (int p = 0; p < NPROTO; p++) fpout[tok * 8 + p] = s[p];
        clsout[tok] = (float)best;
        clsarr[tok] = msrc[tok] ? best : -1;
    }
}

// ---------------- weight convert + transpose: Wt[n*K+k] = bf16(W[k*N+n]) ----
__global__ __launch_bounds__(256) void lft_wconv_kernel(
    const float* W0, const float* W1p, const float* W2p, const float* W3p,
    int K, int N, int nTypes, ushort* dst)
{
    int z = blockIdx.z;
    int li = z / nTypes, mi = z % nTypes;
    const float* srcs[4] = {W0, W1p, W2p, W3p};
    const float* src = srcs[mi] + (size_t)li * K * N;
    ushort* outp = dst + (size_t)z * K * N;
    __shared__ float tile[32][33];
    int k0 = blockIdx.x * 32, n0 = blockIdx.y * 32;
    int t = threadIdx.x;
    int r = t >> 3, c4 = (t & 7) << 2;
    float4 v = *(const float4*)&src[(size_t)(k0 + r) * N + n0 + c4];
    tile[r][c4] = v.x; tile[r][c4 + 1] = v.y; tile[r][c4 + 2] = v.z; tile[r][c4 + 3] = v.w;
    __syncthreads();
    ushort4 o;
    o.x = f2b(tile[c4 + 0][r]);
    o.y = f2b(tile[c4 + 1][r]);
    o.z = f2b(tile[c4 + 2][r]);
    o.w = f2b(tile[c4 + 3][r]);
    *(ushort4*)&outp[(size_t)(n0 + r) * K + k0 + c4] = o;
}

// ---------------- initial fp32 copy + bf16 cast of feat0/feat1 ----------------
__global__ __launch_bounds__(256) void lft_cast_kernel(
    const float* __restrict__ f0, const float* __restrict__ f1,
    float* fa, float* fb, ushort* fab, ushort* fbb)
{
    long idx = ((long)blockIdx.x * 256 + threadIdx.x) * 4;
    const float* src; float* df; ushort* db; long o;
    if (idx < 9830400L) { src = f0; df = fa; db = fab; o = idx; }
    else                { src = f1; df = fb; db = fbb; o = idx - 9830400L; }
    float4 v = *(const float4*)&src[o];
    *(float4*)&df[o] = v;
    ushort4 u; u.x = f2b(v.x); u.y = f2b(v.y); u.z = f2b(v.z); u.w = f2b(v.w);
    *(ushort4*)&db[o] = u;
}

// ---------------- bf16 MFMA GEMM: C[38400,N] = act([A0|A1] @ Wt^T) ----------
// Wt is pre-transposed [N][K]. BM=BN=128, BK=32, 4 waves (2x2), 4x4 MFMA tiles.
// act: 0=none, 1=phi(z)=elu(z)+1, 2=relu. Cf (fp32) / Cb (bf16) optional outs.
__global__ __launch_bounds__(256) void lft_mfma_gemm(
    const ushort* __restrict__ A0, const ushort* __restrict__ A1, int kSplit,
    const ushort* __restrict__ Wt,
    float* Cf, ushort* Cb, int N, int K, int act)
{
    __shared__ ushort As[128 * 40];
    __shared__ ushort Bs[128 * 40];
    int t = threadIdx.x;
    int m0 = blockIdx.y << 7;
    int n0 = blockIdx.x << 7;
    int wave = t >> 6, lane = t & 63;
    int wm = wave >> 1, wn = wave & 1;
    int l16 = lane & 15, quad = lane >> 4;
    floatx4 acc[4][4] = {};
    int rowA = t >> 2;            // 0..63
    int coff = (t & 3) << 3;      // 0,8,16,24
    for (int k0 = 0; k0 < K; k0 += 32) {
        const ushort* Asrc; int kcol, ldA;
        if (k0 < kSplit) { Asrc = A0; kcol = k0;          ldA = kSplit; }
        else             { Asrc = A1; kcol = k0 - kSplit; ldA = K - kSplit; }
        uint4 a0 = *(const uint4*)&Asrc[(size_t)(m0 + rowA) * ldA + kcol + coff];
        uint4 a1 = *(const uint4*)&Asrc[(size_t)(m0 + rowA + 64) * ldA + kcol + coff];
        uint4 b0 = *(const uint4*)&Wt[(size_t)(n0 + rowA) * K + k0 + coff];
        uint4 b1 = *(const uint4*)&Wt[(size_t)(n0 + rowA + 64) * K + k0 + coff];
        __syncthreads();
        *(uint4*)&As[rowA * 40 + coff] = a0;
        *(uint4*)&As[(rowA + 64) * 40 + coff] = a1;
        *(uint4*)&Bs[rowA * 40 + coff] = b0;
        *(uint4*)&Bs[(rowA + 64) * 40 + coff] = b1;
        __syncthreads();
        short8 af[4], bfr[4];
#pragma unroll
        for (int i = 0; i < 4; i++) {
            af[i]  = *(const short8*)&As[(wm * 64 + i * 16 + l16) * 40 + quad * 8];
            bfr[i] = *(const short8*)&Bs[(wn * 64 + i * 16 + l16) * 40 + quad * 8];
        }
#pragma unroll
        for (int i = 0; i < 4; i++)
#pragma unroll
            for (int j = 0; j < 4; j++)
                acc[i][j] = __builtin_amdgcn_mfma_f32_16x16x32_bf16(af[i], bfr[j], acc[i][j], 0, 0, 0);
    }
#pragma unroll
    for (int i = 0; i < 4; i++) {
#pragma unroll
        for (int j = 0; j < 4; j++) {
#pragma unroll
            for (int r = 0; r < 4; r++) {
                float v = acc[i][j][r];
                if (act == 1)      v = v > 0.f ? v + 1.f : __expf(v);
                else if (act == 2) v = fmaxf(v, 0.f);
                long row = m0 + wm * 64 + i * 16 + quad * 4 + r;
                int col = n0 + wn * 64 + j * 16 + l16;
                if (Cf) Cf[row * N + col] = v;
                if (Cb) Cb[row * N + col] = f2b(v);
            }
        }
    }
}

// ---------------- per-class KV / Ksum reduction ----------------
__global__ __launch_bounds__(256) void lft_kv_kernel(
    const float* __restrict__ phik, const float* __restrict__ vmat,
    const int* __restrict__ cls, float* kv, float* ksum)
{
    int chunk = blockIdx.x, h = blockIdx.y, b = blockIdx.z;
    int t = threadIdx.x;
    const int CH = 600;
    int s0 = chunk * CH;
    __shared__ float kb[8][32];
    __shared__ float vb[8][32];
    __shared__ int cb[8];
    int od = t >> 3;
    int oe = (t & 7) << 2;
    int lt = t >> 5, ld = t & 31;
    float acc[NPROTO][4] = {{0.f}};
    float ak[NPROTO] = {0.f};
    for (int s = s0; s < s0 + CH; s += 8) {
        long base = ((long)b * 4800 + s + lt) * 256 + h * 32 + ld;
        float kval = phik[base];
        float vval = vmat[base];
        int cv = (t < 8) ? cls[b * 4800 + s + t] : 0;
        __syncthreads();
        kb[lt][ld] = kval;
        vb[lt][ld] = vval;
        if (t < 8) cb[t] = cv;
        __syncthreads();
#pragma unroll
        for (int j = 0; j < 8; j++) {
            int c = cb[j];
            float kd = kb[j][od];
            float4 vv = *(const float4*)&vb[j][oe];
#pragma unroll
            for (int cc = 0; cc < NPROTO; cc++) {
                float kdm = (c == cc) ? kd : 0.f;
                acc[cc][0] += kdm * vv.x;
                acc[cc][1] += kdm * vv.y;
                acc[cc][2] += kdm * vv.z;
                acc[cc][3] += kdm * vv.w;
                ak[cc] += kdm;
            }
        }
    }
#pragma unroll
    for (int cc = 0; cc < NPROTO; cc++) {
        float* dst = kv + (((long)(b * NPROTO + cc) * 8 + h) << 10) + od * 32 + oe;
        atomicAdd(dst + 0, acc[cc][0]);
        atomicAdd(dst + 1, acc[cc][1]);
        atomicAdd(dst + 2, acc[cc][2]);
        atomicAdd(dst + 3, acc[cc][3]);
        if ((t & 7) == 0)
            atomicAdd(ksum + (((long)(b * NPROTO + cc) * 8 + h) << 5) + od, ak[cc]);
    }
}

// ---------------- msg = (phi_q . kv[c]) / (phi_q . ksum[c] + eps) → bf16 ------
__global__ __launch_bounds__(256) void lft_msg_kernel(
    const float* __restrict__ phiq, const float* __restrict__ kv,
    const float* __restrict__ ksum, const int* __restrict__ cls,
    ushort* msg)
{
    long token = blockIdx.x;
    int t = threadIdx.x;
    int c = cls[token];
    if (c < 0) { msg[token * 256 + t] = 0; return; }
    int b = (int)(token / 4800);
    __shared__ float pq[256];
    pq[t] = phiq[token * 256 + t];
    __syncthreads();
    int h = t >> 5, e = t & 31;
    const float* kvp = kv + (((long)(b * NPROTO + c) * 8 + h) << 10) + e;
    const float* ksp = ksum + (((long)(b * NPROTO + c) * 8 + h) << 5);
    const float* pqh = pq + h * 32;
    float num = 0.f, den = 0.f;
#pragma unroll
    for (int d = 0; d < 32; d++) {
        float p = pqh[d];
        num += p * kvp[d * 32];
        den += p * ksp[d];
    }
    msg[token * 256 + t] = f2b(num / (den + 1e-6f));
}

// ---------------- row LayerNorm (256), optional residual+mask, dual outputs ---
__global__ __launch_bounds__(256) void lft_ln_kernel(
    const float* __restrict__ in, float* outF, ushort* outB,
    const float* __restrict__ g, const float* __restrict__ bb,
    const float* resid, const int* __restrict__ cls)
{
    int wave = threadIdx.x >> 6, lane = threadIdx.x & 63;
    long row = (long)blockIdx.x * 4 + wave;
    float4 x = *(const float4*)&in[row * 256 + lane * 4];
    float s = x.x + x.y + x.z + x.w;
#pragma unroll
    for (int o = 32; o >= 1; o >>= 1) s += __shfl_xor(s, o, 64);
    float mean = s * (1.0f / 256.0f);
    float dx = x.x - mean, dy = x.y - mean, dz = x.z - mean, dw = x.w - mean;
    float vs = dx * dx + dy * dy + dz * dz + dw * dw;
#pragma unroll
    for (int o = 32; o >= 1; o >>= 1) vs += __shfl_xor(vs, o, 64);
    float r = rsqrtf(vs * (1.0f / 256.0f) + 1e-5f);
    float4 gv = *(const float4*)&g[lane * 4];
    float4 bv = *(const float4*)&bb[lane * 4];
    float4 y;
    y.x = dx * r * gv.x + bv.x;
    y.y = dy * r * gv.y + bv.y;
    y.z = dz * r * gv.z + bv.z;
    y.w = dw * r * gv.w + bv.w;
    if (resid) {
        float4 xr = *(const float4*)&resid[row * 256 + lane * 4];
        if (cls[row] >= 0) { y.x += xr.x; y.y += xr.y; y.z += xr.z; y.w += xr.w; }
        else y = xr;
    }
    if (outF) *(float4*)&outF[row * 256 + lane * 4] = y;
    if (outB) {
        ushort4 u; u.x = f2b(y.x); u.y = f2b(y.y); u.z = f2b(y.z); u.w = f2b(y.w);
        *(ushort4*)&outB[row * 256 + lane * 4] = u;
    }
}

extern "C" void kernel_launch(void* const* d_in, const int* in_sizes, int n_in,
                              void* d_out, int out_size, void* d_ws, size_t ws_size,
                              hipStream_t stream)
{
    (void)in_sizes; (void)n_in; (void)out_size; (void)ws_size;
    const float* feat0 = (const float*)d_in[0];
    const float* feat1 = (const float*)d_in[1];
    const int*   mask0 = (const int*)d_in[2];
    const int*   mask1 = (const int*)d_in[3];
    const float* f0wo  = (const float*)d_in[4];
    const float* f1wo  = (const float*)d_in[5];
    const float* proto = (const float*)d_in[6];
    const float* Wq = (const float*)d_in[7];
    const float* Wk = (const float*)d_in[8];
    const float* Wv = (const float*)d_in[9];
    const float* Wm = (const float*)d_in[10];
    const float* W1 = (const float*)d_in[11];
    const float* W2 = (const float*)d_in[12];
    const float* g1 = (const float*)d_in[13];
    const float* b1 = (const float*)d_in[14];
    const float* g2 = (const float*)d_in[15];
    const float* b2 = (const float*)d_in[16];
    float* out = (float*)d_out;
    float* ws = (float*)d_ws;

    const long FSZ = 9830400L;           // 8*4800*256
    float* fa   = ws;                    // fp32 master feat0
    float* fb   = ws + FSZ;              // fp32 master feat1
    float* qb   = ws + 2 * FSZ;          // phi_q ; later W2 output
    float* kbuf = ws + 3 * FSZ;          // phi_k ; later Wm output
    float* vbuf = ws + 4 * FSZ;          // v ; later reused as hid_bf (bf16, 2*FSZ elems)
    ushort* ub  = (ushort*)(ws + 5 * FSZ);
    ushort* fa_bf  = ub;                 // bf16 shadow of fa
    ushort* fb_bf  = ub + FSZ;           // bf16 shadow of fb
    ushort* msg_bf = ub + 2 * FSZ;       // msg bf16; later LN1 bf16 out
    ushort* wb     = ub + 3 * FSZ;       // bf16 transposed weights
    ushort* wb1    = wb + 16 * 65536;    // W1^T per layer [512][512]
    ushort* wb2    = wb1 + 4 * 262144;   // W2^T per layer [256][512]
    float* kvb = (float*)(wb2 + 4 * 131072);   // [B,NP,H,D,D] = 524288 f
    float* ksb = kvb + 524288;                 // [B,NP,H,D]   = 16384 f
    int* cls0 = (int*)(ksb + 16384);
    int* cls1 = cls0 + 38400;
    ushort* hid_bf = (ushort*)vbuf;      // [38400,512] bf16 (reuses vbuf after kv)

    // one-time per launch: weight convert+transpose, feat copy+cast, classes
    lft_wconv_kernel<<<dim3(8, 8, 16), 256, 0, stream>>>(Wq, Wk, Wv, Wm, 256, 256, 4, wb);
    lft_wconv_kernel<<<dim3(16, 16, 4), 256, 0, stream>>>(W1, W1, W1, W1, 512, 512, 1, wb1);
    lft_wconv_kernel<<<dim3(16, 8, 4), 256, 0, stream>>>(W2, W2, W2, W2, 512, 256, 1, wb2);
    lft_cast_kernel<<<19200, 256, 0, stream>>>(feat0, feat1, fa, fb, fa_bf, fb_bf);
    hipMemcpyAsync(out + 20352000L, proto, 2048 * 4, hipMemcpyDeviceToDevice, stream);
    lft_class_kernel<<<19200, 256, 0, stream>>>(f0wo, f1wo, mask0, mask1, proto,
                                                out, cls0, cls1);

    for (int li = 0; li < 4; li++) {
        const ushort* wq = wb + (size_t)(li * 4 + 0) * 65536;
        const ushort* wk = wb + (size_t)(li * 4 + 1) * 65536;
        const ushort* wv = wb + (size_t)(li * 4 + 2) * 65536;
        const ushort* wm = wb + (size_t)(li * 4 + 3) * 65536;
        const ushort* w1 = wb1 + (size_t)li * 262144;
        const ushort* w2 = wb2 + (size_t)li * 131072;
        const float* g1p = g1 + li * 256; const float* b1p = b1 + li * 256;
        const float* g2p = g2 + li * 256; const float* b2p = b2 + li * 256;

        auto call = [&](float* x, ushort* x_bf, ushort* s_bf,
                        const int* clsx, const int* clssrc) {
            dim3 blk(256);
            dim3 gA(2, 300), gB(4, 300);
            // q = phi(x@Wq), k = phi(src@Wk), v = src@Wv
            lft_mfma_gemm<<<gA, blk, 0, stream>>>(x_bf, x_bf, 256, wq, qb,   nullptr, 256, 256, 1);
            lft_mfma_gemm<<<gA, blk, 0, stream>>>(s_bf, s_bf, 256, wk, kbuf, nullptr, 256, 256, 1);
            lft_mfma_gemm<<<gA, blk, 0, stream>>>(s_bf, s_bf, 256, wv, vbuf, nullptr, 256, 256, 0);
            hipMemsetAsync(kvb, 0, (524288 + 16384) * 4, stream);
            lft_kv_kernel<<<dim3(8, 8, 8), blk, 0, stream>>>(kbuf, vbuf, clssrc, kvb, ksb);
            lft_msg_kernel<<<38400, blk, 0, stream>>>(qb, kvb, ksb, clsx, msg_bf);
            // msg = LN(msg @ Wm)*g1+b1  (LN out bf16 only, reuses msg_bf)
            lft_mfma_gemm<<<gA, blk, 0, stream>>>(msg_bf, msg_bf, 256, wm, kbuf, nullptr, 256, 256, 0);
            lft_ln_kernel<<<9600, blk, 0, stream>>>(kbuf, nullptr, msg_bf, g1p, b1p, nullptr, nullptr);
            // hid = relu([x|msg]@W1) (bf16) ; m = hid@W2 ; x = valid ? x+LN(m) : x
            lft_mfma_gemm<<<gB, blk, 0, stream>>>(x_bf, msg_bf, 256, w1, nullptr, hid_bf, 512, 512, 2);
            lft_mfma_gemm<<<gA, blk, 0, stream>>>(hid_bf, hid_bf, 512, w2, qb, nullptr, 256, 512, 0);
            lft_ln_kernel<<<9600, blk, 0, stream>>>(qb, x, x_bf, g2p, b2p, x, clsx);
        };

        if ((li & 1) == 0) {           // self-self
            call(fa, fa_bf, fa_bf, cls0, cls0);
            call(fb, fb_bf, fb_bf, cls1, cls1);
        } else {                       // cross-self: new0 first, then feat1 vs updated feat0
            call(fa, fa_bf, fb_bf, cls0, cls1);
            call(fb, fb_bf, fa_bf, cls1, cls0);
        }
    }
    hipMemcpyAsync(out,       fa, FSZ * 4, hipMemcpyDeviceToDevice, stream);
    hipMemcpyAsync(out + FSZ, fb, FSZ * 4, hipMemcpyDeviceToDevice, stream);
}

// Round 3
// 2547.932 us; speedup vs baseline: 3.0809x; 1.3733x over previous
//
#include <hip/hip_runtime.h>
#include <math.h>

#define NPROTO 8
#define KV_NCH 4

typedef __attribute__((ext_vector_type(8))) short short8;
typedef __attribute__((ext_vector_type(4))) float floatx4;

static __device__ __forceinline__ ushort f2b(float f) {
    unsigned u = __builtin_bit_cast(unsigned, f);
    unsigned r = (u + 0x7fffu + ((u >> 16) & 1u)) >> 16;
    return (ushort)r;
}

// ---------------- prototype projection / argmax-class kernel ----------------
__global__ __launch_bounds__(256) void lft_class_kernel(
    const float* __restrict__ f0wo, const float* __restrict__ f1wo,
    const int* __restrict__ mask0, const int* __restrict__ mask1,
    const float* __restrict__ proto,
    float* out, int* cls0, int* cls1)
{
    __shared__ float pr[2048];
    int t = threadIdx.x;
    *(float4*)&pr[t * 4]        = *(const float4*)&proto[t * 4];
    *(float4*)&pr[1024 + t * 4] = *(const float4*)&proto[1024 + t * 4];
    __syncthreads();
    int wave = t >> 6, lane = t & 63;
    long token = (long)blockIdx.x * 4 + wave;
    const float* fsrc; const int* msrc; float* fpout; float* clsout; int* clsarr; long tok;
    if (token < 38400) {
        tok = token; fsrc = f0wo; msrc = mask0;
        fpout = out + 19737600L; clsout = out + 19660800L; clsarr = cls0;
    } else {
        tok = token - 38400; fsrc = f1wo; msrc = mask1;
        fpout = out + 20044800L; clsout = out + 19699200L; clsarr = cls1;
    }
    float4 f = *(const float4*)&fsrc[tok * 256 + lane * 4];
    float s[NPROTO];
#pragma unroll
    for (int p = 0; p < NPROTO; p++) {
        float4 pv = *(const float4*)&pr[p * 256 + lane * 4];
        float d = f.x * pv.x + f.y * pv.y + f.z * pv.z + f.w * pv.w;
#pragma unroll
        for (int o = 32; o >= 1; o >>= 1) d += __shfl_xor(d, o, 64);
        s[p] = d;
    }
    if (lane == 0) {
        int best = 0; float bv = s[0];
#pragma unroll
        for (int p = 1; p < NPROTO; p++) { if (s[p] > bv) { bv = s[p]; best = p; } }
#pragma unroll
        for (int p = 0; p < NPROTO; p++) fpout[tok * 8 + p] = s[p];
        clsout[tok] = (float)best;
        clsarr[tok] = msrc[tok] ? best : -1;
    }
}

// ---------------- counting sort of tokens by (batch,class) -------------------
// one block per (list, b); produces tl[b][...] class-segmented + meta(off,cnt)
__global__ __launch_bounds__(256) void lft_sort_kernel(
    const int* __restrict__ cls0, const int* __restrict__ cls1,
    int* tl0, int* tl1, int* meta)
{
    int g = blockIdx.x; int L = g >> 3, b = g & 7;
    const int* cls = (L ? cls1 : cls0) + b * 4800;
    int* tl = (L ? tl1 : tl0) + b * 4800;
    int* mt = meta + (L * 8 + b) * 16;
    __shared__ int cnt[8], base[8], pos[8];
    int t = threadIdx.x;
    if (t < 8) cnt[t] = 0;
    __syncthreads();
    for (int tok = t; tok < 4800; tok += 256) {
        int c = cls[tok];
        if (c >= 0) atomicAdd(&cnt[c], 1);
    }
    __syncthreads();
    if (t == 0) {
        int s = 0;
        for (int c = 0; c < 8; c++) { base[c] = s; pos[c] = s; s += cnt[c]; }
    }
    __syncthreads();
    if (t < 8) { mt[t * 2] = base[t]; mt[t * 2 + 1] = cnt[t]; }
    for (int tok = t; tok < 4800; tok += 256) {
        int c = cls[tok];
        if (c >= 0) { int p = atomicAdd(&pos[c], 1); tl[p] = tok; }
    }
}

// ---------------- weight convert + transpose: Wt[n*K+k] = bf16(W[k*N+n]) ----
__global__ __launch_bounds__(256) void lft_wconv_kernel(
    const float* W0, const float* W1p, const float* W2p, const float* W3p,
    int K, int N, int nTypes, ushort* dst)
{
    int z = blockIdx.z;
    int li = z / nTypes, mi = z % nTypes;
    const float* srcs[4] = {W0, W1p, W2p, W3p};
    const float* src = srcs[mi] + (size_t)li * K * N;
    ushort* outp = dst + (size_t)z * K * N;
    __shared__ float tile[32][33];
    int k0 = blockIdx.x * 32, n0 = blockIdx.y * 32;
    int t = threadIdx.x;
    int r = t >> 3, c4 = (t & 7) << 2;
    float4 v = *(const float4*)&src[(size_t)(k0 + r) * N + n0 + c4];
    tile[r][c4] = v.x; tile[r][c4 + 1] = v.y; tile[r][c4 + 2] = v.z; tile[r][c4 + 3] = v.w;
    __syncthreads();
    ushort4 o;
    o.x = f2b(tile[c4 + 0][r]);
    o.y = f2b(tile[c4 + 1][r]);
    o.z = f2b(tile[c4 + 2][r]);
    o.w = f2b(tile[c4 + 3][r]);
    *(ushort4*)&outp[(size_t)(n0 + r) * K + k0 + c4] = o;
}

// ---------------- initial fp32 copy + bf16 cast of feat0/feat1 ----------------
__global__ __launch_bounds__(256) void lft_cast_kernel(
    const float* __restrict__ f0, const float* __restrict__ f1,
    float* fa, float* fb, ushort* fab, ushort* fbb)
{
    long idx = ((long)blockIdx.x * 256 + threadIdx.x) * 4;
    const float* src; float* df; ushort* db; long o;
    if (idx < 9830400L) { src = f0; df = fa; db = fab; o = idx; }
    else                { src = f1; df = fb; db = fbb; o = idx - 9830400L; }
    float4 v = *(const float4*)&src[o];
    *(float4*)&df[o] = v;
    ushort4 u; u.x = f2b(v.x); u.y = f2b(v.y); u.z = f2b(v.z); u.w = f2b(v.w);
    *(ushort4*)&db[o] = u;
}

// ---------------- bf16 MFMA GEMM: C[38400,N] = act([A0|A1] @ Wt^T) ----------
__global__ __launch_bounds__(256) void lft_mfma_gemm(
    const ushort* __restrict__ A0, const ushort* __restrict__ A1, int kSplit,
    const ushort* __restrict__ Wt,
    float* Cf, ushort* Cb, int N, int K, int act)
{
    __shared__ ushort As[128 * 40];
    __shared__ ushort Bs[128 * 40];
    int t = threadIdx.x;
    int m0 = blockIdx.y << 7;
    int n0 = blockIdx.x << 7;
    int wave = t >> 6, lane = t & 63;
    int wm = wave >> 1, wn = wave & 1;
    int l16 = lane & 15, quad = lane >> 4;
    floatx4 acc[4][4] = {};
    int rowA = t >> 2;            // 0..63
    int coff = (t & 3) << 3;      // 0,8,16,24
    for (int k0 = 0; k0 < K; k0 += 32) {
        const ushort* Asrc; int kcol, ldA;
        if (k0 < kSplit) { Asrc = A0; kcol = k0;          ldA = kSplit; }
        else             { Asrc = A1; kcol = k0 - kSplit; ldA = K - kSplit; }
        uint4 a0 = *(const uint4*)&Asrc[(size_t)(m0 + rowA) * ldA + kcol + coff];
        uint4 a1 = *(const uint4*)&Asrc[(size_t)(m0 + rowA + 64) * ldA + kcol + coff];
        uint4 b0 = *(const uint4*)&Wt[(size_t)(n0 + rowA) * K + k0 + coff];
        uint4 b1 = *(const uint4*)&Wt[(size_t)(n0 + rowA + 64) * K + k0 + coff];
        __syncthreads();
        *(uint4*)&As[rowA * 40 + coff] = a0;
        *(uint4*)&As[(rowA + 64) * 40 + coff] = a1;
        *(uint4*)&Bs[rowA * 40 + coff] = b0;
        *(uint4*)&Bs[(rowA + 64) * 40 + coff] = b1;
        __syncthreads();
        short8 af[4], bfr[4];
#pragma unroll
        for (int i = 0; i < 4; i++) {
            af[i]  = *(const short8*)&As[(wm * 64 + i * 16 + l16) * 40 + quad * 8];
            bfr[i] = *(const short8*)&Bs[(wn * 64 + i * 16 + l16) * 40 + quad * 8];
        }
#pragma unroll
        for (int i = 0; i < 4; i++)
#pragma unroll
            for (int j = 0; j < 4; j++)
                acc[i][j] = __builtin_amdgcn_mfma_f32_16x16x32_bf16(af[i], bfr[j], acc[i][j], 0, 0, 0);
    }
#pragma unroll
    for (int i = 0; i < 4; i++) {
#pragma unroll
        for (int j = 0; j < 4; j++) {
#pragma unroll
            for (int r = 0; r < 4; r++) {
                float v = acc[i][j][r];
                if (act == 1)      v = v > 0.f ? v + 1.f : __expf(v);
                else if (act == 2) v = fmaxf(v, 0.f);
                long row = m0 + wm * 64 + i * 16 + quad * 4 + r;
                int col = n0 + wn * 64 + j * 16 + l16;
                if (Cf) Cf[row * N + col] = v;
                if (Cb) Cb[row * N + col] = f2b(v);
            }
        }
    }
}

// ---------------- per-class KV / Ksum reduction (class-sorted token lists) ----
// grid (chunk=KV_NCH, c=8, b*8+h=64); block 256; no class predication.
__global__ __launch_bounds__(256) void lft_kv_kernel(
    const float* __restrict__ phik, const float* __restrict__ vmat,
    const int* __restrict__ tlist, const int* __restrict__ meta,
    float* kv, float* ksum)
{
    int chunk = blockIdx.x, c = blockIdx.y;
    int b = blockIdx.z >> 3, h = blockIdx.z & 7;
    int off = meta[(b * 8 + c) * 2], n = meta[(b * 8 + c) * 2 + 1];
    int per = (n + KV_NCH - 1) / KV_NCH;
    int s0 = chunk * per;
    int s1 = min(s0 + per, n);
    if (s0 >= s1) return;
    const int* tl = tlist + b * 4800 + off;
    int t = threadIdx.x;
    __shared__ float kb[8][32];
    __shared__ float vb[8][32];
    int od = t >> 3, oe = (t & 7) << 2;
    int lt = t >> 5, ld = t & 31;
    float a0 = 0.f, a1 = 0.f, a2 = 0.f, a3 = 0.f, ak = 0.f;
    for (int s = s0; s < s1; s += 8) {
        float kval = 0.f, vval = 0.f;
        if (s + lt < s1) {
            int tok = tl[s + lt];
            long bse = ((long)b * 4800 + tok) * 256 + h * 32 + ld;
            kval = phik[bse];
            vval = vmat[bse];
        }
        __syncthreads();
        kb[lt][ld] = kval;
        vb[lt][ld] = vval;
        __syncthreads();
#pragma unroll
        for (int j = 0; j < 8; j++) {
            float kd = kb[j][od];
            float4 vv = *(const float4*)&vb[j][oe];
            a0 += kd * vv.x; a1 += kd * vv.y; a2 += kd * vv.z; a3 += kd * vv.w;
            ak += kd;
        }
    }
    float* dst = kv + (((long)(b * NPROTO + c) * 8 + h) << 10) + od * 32 + oe;
    atomicAdd(dst + 0, a0);
    atomicAdd(dst + 1, a1);
    atomicAdd(dst + 2, a2);
    atomicAdd(dst + 3, a3);
    if ((t & 7) == 0)
        atomicAdd(ksum + (((long)(b * NPROTO + c) * 8 + h) << 5) + od, ak);
}

// ---------------- msg = (phi_q . kv[c]) / (phi_q . ksum[c] + eps) → bf16 ------
__global__ __launch_bounds__(256) void lft_msg_kernel(
    const float* __restrict__ phiq, const float* __restrict__ kv,
    const float* __restrict__ ksum, const int* __restrict__ cls,
    ushort* msg)
{
    long token = blockIdx.x;
    int t = threadIdx.x;
    int c = cls[token];
    if (c < 0) { msg[token * 256 + t] = 0; return; }
    int b = (int)(token / 4800);
    __shared__ float pq[256];
    pq[t] = phiq[token * 256 + t];
    __syncthreads();
    int h = t >> 5, e = t & 31;
    const float* kvp = kv + (((long)(b * NPROTO + c) * 8 + h) << 10) + e;
    const float* ksp = ksum + (((long)(b * NPROTO + c) * 8 + h) << 5);
    const float* pqh = pq + h * 32;
    float num = 0.f, den = 0.f;
#pragma unroll
    for (int d = 0; d < 32; d++) {
        float p = pqh[d];
        num += p * kvp[d * 32];
        den += p * ksp[d];
    }
    msg[token * 256 + t] = f2b(num / (den + 1e-6f));
}

// ---------------- row LayerNorm (256), optional residual+mask, dual outputs ---
__global__ __launch_bounds__(256) void lft_ln_kernel(
    const float* __restrict__ in, float* outF, ushort* outB,
    const float* __restrict__ g, const float* __restrict__ bb,
    const float* resid, const int* __restrict__ cls)
{
    int wave = threadIdx.x >> 6, lane = threadIdx.x & 63;
    long row = (long)blockIdx.x * 4 + wave;
    float4 x = *(const float4*)&in[row * 256 + lane * 4];
    float s = x.x + x.y + x.z + x.w;
#pragma unroll
    for (int o = 32; o >= 1; o >>= 1) s += __shfl_xor(s, o, 64);
    float mean = s * (1.0f / 256.0f);
    float dx = x.x - mean, dy = x.y - mean, dz = x.z - mean, dw = x.w - mean;
    float vs = dx * dx + dy * dy + dz * dz + dw * dw;
#pragma unroll
    for (int o = 32; o >= 1; o >>= 1) vs += __shfl_xor(vs, o, 64);
    float r = rsqrtf(vs * (1.0f / 256.0f) + 1e-5f);
    float4 gv = *(const float4*)&g[lane * 4];
    float4 bv = *(const float4*)&bb[lane * 4];
    float4 y;
    y.x = dx * r * gv.x + bv.x;
    y.y = dy * r * gv.y + bv.y;
    y.z = dz * r * gv.z + bv.z;
    y.w = dw * r * gv.w + bv.w;
    if (resid) {
        float4 xr = *(const float4*)&resid[row * 256 + lane * 4];
        if (cls[row] >= 0) { y.x += xr.x; y.y += xr.y; y.z += xr.z; y.w += xr.w; }
        else y = xr;
    }
    if (outF) *(float4*)&outF[row * 256 + lane * 4] = y;
    if (outB) {
        ushort4 u; u.x = f2b(y.x); u.y = f2b(y.y); u.z = f2b(y.z); u.w = f2b(y.w);
        *(ushort4*)&outB[row * 256 + lane * 4] = u;
    }
}

extern "C" void kernel_launch(void* const* d_in, const int* in_sizes, int n_in,
                              void* d_out, int out_size, void* d_ws, size_t ws_size,
                              hipStream_t stream)
{
    (void)in_sizes; (void)n_in; (void)out_size; (void)ws_size;
    const float* feat0 = (const float*)d_in[0];
    const float* feat1 = (const float*)d_in[1];
    const int*   mask0 = (const int*)d_in[2];
    const int*   mask1 = (const int*)d_in[3];
    const float* f0wo  = (const float*)d_in[4];
    const float* f1wo  = (const float*)d_in[5];
    const float* proto = (const float*)d_in[6];
    const float* Wq = (const float*)d_in[7];
    const float* Wk = (const float*)d_in[8];
    const float* Wv = (const float*)d_in[9];
    const float* Wm = (const float*)d_in[10];
    const float* W1 = (const float*)d_in[11];
    const float* W2 = (const float*)d_in[12];
    const float* g1 = (const float*)d_in[13];
    const float* b1 = (const float*)d_in[14];
    const float* g2 = (const float*)d_in[15];
    const float* b2 = (const float*)d_in[16];
    float* out = (float*)d_out;
    float* ws = (float*)d_ws;

    const long FSZ = 9830400L;           // 8*4800*256
    float* fa   = ws;                    // fp32 master feat0
    float* fb   = ws + FSZ;              // fp32 master feat1
    float* qb   = ws + 2 * FSZ;          // phi_q ; later W2 output
    float* kbuf = ws + 3 * FSZ;          // phi_k ; later Wm output
    float* vbuf = ws + 4 * FSZ;          // v ; later reused as hid_bf (bf16)
    ushort* ub  = (ushort*)(ws + 5 * FSZ);
    ushort* fa_bf  = ub;                 // bf16 shadow of fa
    ushort* fb_bf  = ub + FSZ;           // bf16 shadow of fb
    ushort* msg_bf = ub + 2 * FSZ;       // msg bf16; later LN1 bf16 out
    ushort* wb     = ub + 3 * FSZ;       // bf16 transposed weights
    ushort* wb1    = wb + 16 * 65536;    // W1^T per layer [512][512]
    ushort* wb2    = wb1 + 4 * 262144;   // W2^T per layer [256][512]
    float* kvb = (float*)(wb2 + 4 * 131072);   // [B,NP,H,D,D] = 524288 f
    float* ksb = kvb + 524288;                 // [B,NP,H,D]   = 16384 f
    int* cls0 = (int*)(ksb + 16384);
    int* cls1 = cls0 + 38400;
    int* tl0  = cls1 + 38400;            // class-sorted token lists
    int* tl1  = tl0 + 38400;
    int* meta = tl1 + 38400;             // [2][8][8][2] (off,cnt)
    ushort* hid_bf = (ushort*)vbuf;      // [38400,512] bf16 (reuses vbuf after kv)

    // one-time per launch: weights, feat copy+cast, classes, class sort
    lft_wconv_kernel<<<dim3(8, 8, 16), 256, 0, stream>>>(Wq, Wk, Wv, Wm, 256, 256, 4, wb);
    lft_wconv_kernel<<<dim3(16, 16, 4), 256, 0, stream>>>(W1, W1, W1, W1, 512, 512, 1, wb1);
    lft_wconv_kernel<<<dim3(16, 8, 4), 256, 0, stream>>>(W2, W2, W2, W2, 512, 256, 1, wb2);
    lft_cast_kernel<<<19200, 256, 0, stream>>>(feat0, feat1, fa, fb, fa_bf, fb_bf);
    hipMemcpyAsync(out + 20352000L, proto, 2048 * 4, hipMemcpyDeviceToDevice, stream);
    lft_class_kernel<<<19200, 256, 0, stream>>>(f0wo, f1wo, mask0, mask1, proto,
                                                out, cls0, cls1);
    lft_sort_kernel<<<16, 256, 0, stream>>>(cls0, cls1, tl0, tl1, meta);

    for (int li = 0; li < 4; li++) {
        const ushort* wq = wb + (size_t)(li * 4 + 0) * 65536;
        const ushort* wk = wb + (size_t)(li * 4 + 1) * 65536;
        const ushort* wv = wb + (size_t)(li * 4 + 2) * 65536;
        const ushort* wm = wb + (size_t)(li * 4 + 3) * 65536;
        const ushort* w1 = wb1 + (size_t)li * 262144;
        const ushort* w2 = wb2 + (size_t)li * 131072;
        const float* g1p = g1 + li * 256; const float* b1p = b1 + li * 256;
        const float* g2p = g2 + li * 256; const float* b2p = b2 + li * 256;

        auto call = [&](float* x, ushort* x_bf, ushort* s_bf,
                        const int* clsx, const int* tls, const int* mts) {
            dim3 blk(256);
            dim3 gA(2, 300), gB(4, 300);
            // q = phi(x@Wq), k = phi(src@Wk), v = src@Wv
            lft_mfma_gemm<<<gA, blk, 0, stream>>>(x_bf, x_bf, 256, wq, qb,   nullptr, 256, 256, 1);
            lft_mfma_gemm<<<gA, blk, 0, stream>>>(s_bf, s_bf, 256, wk, kbuf, nullptr, 256, 256, 1);
            lft_mfma_gemm<<<gA, blk, 0, stream>>>(s_bf, s_bf, 256, wv, vbuf, nullptr, 256, 256, 0);
            hipMemsetAsync(kvb, 0, (524288 + 16384) * 4, stream);
            lft_kv_kernel<<<dim3(KV_NCH, 8, 64), blk, 0, stream>>>(kbuf, vbuf, tls, mts, kvb, ksb);
            lft_msg_kernel<<<38400, blk, 0, stream>>>(qb, kvb, ksb, clsx, msg_bf);
            // msg = LN(msg @ Wm)*g1+b1  (LN out bf16 only, reuses msg_bf)
            lft_mfma_gemm<<<gA, blk, 0, stream>>>(msg_bf, msg_bf, 256, wm, kbuf, nullptr, 256, 256, 0);
            lft_ln_kernel<<<9600, blk, 0, stream>>>(kbuf, nullptr, msg_bf, g1p, b1p, nullptr, nullptr);
            // hid = relu([x|msg]@W1) (bf16) ; m = hid@W2 ; x = valid ? x+LN(m) : x
            lft_mfma_gemm<<<gB, blk, 0, stream>>>(x_bf, msg_bf, 256, w1, nullptr, hid_bf, 512, 512, 2);
            lft_mfma_gemm<<<gA, blk, 0, stream>>>(hid_bf, hid_bf, 512, w2, qb, nullptr, 256, 512, 0);
            lft_ln_kernel<<<9600, blk, 0, stream>>>(qb, x, x_bf, g2p, b2p, x, clsx);
        };

        if ((li & 1) == 0) {           // self-self
            call(fa, fa_bf, fa_bf, cls0, tl0, meta);
            call(fb, fb_bf, fb_bf, cls1, tl1, meta + 128);
        } else {                       // cross-self
            call(fa, fa_bf, fb_bf, cls0, tl1, meta + 128);
            call(fb, fb_bf, fa_bf, cls1, tl0, meta);
        }
    }
    hipMemcpyAsync(out,       fa, FSZ * 4, hipMemcpyDeviceToDevice, stream);
    hipMemcpyAsync(out + FSZ, fb, FSZ * 4, hipMemcpyDeviceToDevice, stream);
}

// Round 6
// 2194.676 us; speedup vs baseline: 3.5768x; 1.1610x over previous
//
#include <hip/hip_runtime.h>
#include <math.h>

#define NPROTO 8
#define KV_NCH 4
#define MSG_NCH 8

typedef __attribute__((ext_vector_type(8))) short short8;
typedef __attribute__((ext_vector_type(4))) float floatx4;

static __device__ __forceinline__ ushort f2b(float f) {
    unsigned u = __builtin_bit_cast(unsigned, f);
    unsigned r = (u + 0x7fffu + ((u >> 16) & 1u)) >> 16;
    return (ushort)r;
}

// ---------------- prototype projection / argmax-class kernel ----------------
__global__ __launch_bounds__(256) void lft_class_kernel(
    const float* __restrict__ f0wo, const float* __restrict__ f1wo,
    const int* __restrict__ mask0, const int* __restrict__ mask1,
    const float* __restrict__ proto,
    float* out, int* cls0, int* cls1)
{
    __shared__ float pr[2048];
    int t = threadIdx.x;
    *(float4*)&pr[t * 4]        = *(const float4*)&proto[t * 4];
    *(float4*)&pr[1024 + t * 4] = *(const float4*)&proto[1024 + t * 4];
    __syncthreads();
    int wave = t >> 6, lane = t & 63;
    long token = (long)blockIdx.x * 4 + wave;
    const float* fsrc; const int* msrc; float* fpout; float* clsout; int* clsarr; long tok;
    if (token < 38400) {
        tok = token; fsrc = f0wo; msrc = mask0;
        fpout = out + 19737600L; clsout = out + 19660800L; clsarr = cls0;
    } else {
        tok = token - 38400; fsrc = f1wo; msrc = mask1;
        fpout = out + 20044800L; clsout = out + 19699200L; clsarr = cls1;
    }
    float4 f = *(const float4*)&fsrc[tok * 256 + lane * 4];
    float s[NPROTO];
#pragma unroll
    for (int p = 0; p < NPROTO; p++) {
        float4 pv = *(const float4*)&pr[p * 256 + lane * 4];
        float d = f.x * pv.x + f.y * pv.y + f.z * pv.z + f.w * pv.w;
#pragma unroll
        for (int o = 32; o >= 1; o >>= 1) d += __shfl_xor(d, o, 64);
        s[p] = d;
    }
    if (lane == 0) {
        int best = 0; float bv = s[0];
#pragma unroll
        for (int p = 1; p < NPROTO; p++) { if (s[p] > bv) { bv = s[p]; best = p; } }
#pragma unroll
        for (int p = 0; p < NPROTO; p++) fpout[tok * 8 + p] = s[p];
        clsout[tok] = (float)best;
        clsarr[tok] = msrc[tok] ? best : -1;
    }
}

// ---------------- counting sort of tokens by (batch,class) -------------------
__global__ __launch_bounds__(256) void lft_sort_kernel(
    const int* __restrict__ cls0, const int* __restrict__ cls1,
    int* tl0, int* tl1, int* meta)
{
    int g = blockIdx.x; int L = g >> 3, b = g & 7;
    const int* cls = (L ? cls1 : cls0) + b * 4800;
    int* tl = (L ? tl1 : tl0) + b * 4800;
    int* mt = meta + (L * 8 + b) * 16;
    __shared__ int cnt[8], base[8], pos[8];
    int t = threadIdx.x;
    if (t < 8) cnt[t] = 0;
    __syncthreads();
    for (int tok = t; tok < 4800; tok += 256) {
        int c = cls[tok];
        if (c >= 0) atomicAdd(&cnt[c], 1);
    }
    __syncthreads();
    if (t == 0) {
        int s = 0;
        for (int c = 0; c < 8; c++) { base[c] = s; pos[c] = s; s += cnt[c]; }
    }
    __syncthreads();
    if (t < 8) { mt[t * 2] = base[t]; mt[t * 2 + 1] = cnt[t]; }
    for (int tok = t; tok < 4800; tok += 256) {
        int c = cls[tok];
        if (c >= 0) { int p = atomicAdd(&pos[c], 1); tl[p] = tok; }
    }
}

// ---------------- weight convert + transpose: Wt[n*K+k] = bf16(W[k*N+n]) ----
__global__ __launch_bounds__(256) void lft_wconv_kernel(
    const float* W0, const float* W1p, const float* W2p, const float* W3p,
    int K, int N, int nTypes, ushort* dst)
{
    int z = blockIdx.z;
    int li = z / nTypes, mi = z % nTypes;
    const float* srcs[4] = {W0, W1p, W2p, W3p};
    const float* src = srcs[mi] + (size_t)li * K * N;
    ushort* outp = dst + (size_t)z * K * N;
    __shared__ float tile[32][33];
    int k0 = blockIdx.x * 32, n0 = blockIdx.y * 32;
    int t = threadIdx.x;
    int r = t >> 3, c4 = (t & 7) << 2;
    float4 v = *(const float4*)&src[(size_t)(k0 + r) * N + n0 + c4];
    tile[r][c4] = v.x; tile[r][c4 + 1] = v.y; tile[r][c4 + 2] = v.z; tile[r][c4 + 3] = v.w;
    __syncthreads();
    ushort4 o;
    o.x = f2b(tile[c4 + 0][r]);
    o.y = f2b(tile[c4 + 1][r]);
    o.z = f2b(tile[c4 + 2][r]);
    o.w = f2b(tile[c4 + 3][r]);
    *(ushort4*)&outp[(size_t)(n0 + r) * K + k0 + c4] = o;
}

// ---------------- bf16 cast of feat0/feat1 (shadows only) ----------------
__global__ __launch_bounds__(256) void lft_cast_kernel(
    const float* __restrict__ f0, const float* __restrict__ f1,
    ushort* fab, ushort* fbb)
{
    long idx = ((long)blockIdx.x * 256 + threadIdx.x) * 4;
    const float* src; ushort* db; long o;
    if (idx < 9830400L) { src = f0; db = fab; o = idx; }
    else                { src = f1; db = fbb; o = idx - 9830400L; }
    float4 v = *(const float4*)&src[o];
    ushort4 u; u.x = f2b(v.x); u.y = f2b(v.y); u.z = f2b(v.z); u.w = f2b(v.w);
    *(ushort4*)&db[o] = u;
}

// ---------------- bf16 MFMA GEMM: C[38400,N] = act([A0|A1] @ Wt^T) ----------
__global__ __launch_bounds__(256) void lft_mfma_gemm(
    const ushort* __restrict__ A0, const ushort* __restrict__ A1, int kSplit,
    const ushort* __restrict__ Wt,
    float* Cf, ushort* Cb, int N, int K, int act)
{
    __shared__ ushort As[128 * 40];
    __shared__ ushort Bs[128 * 40];
    int t = threadIdx.x;
    int m0 = blockIdx.y << 7;
    int n0 = blockIdx.x << 7;
    int wave = t >> 6, lane = t & 63;
    int wm = wave >> 1, wn = wave & 1;
    int l16 = lane & 15, quad = lane >> 4;
    floatx4 acc[4][4] = {};
    int rowA = t >> 2;            // 0..63
    int coff = (t & 3) << 3;      // 0,8,16,24
    for (int k0 = 0; k0 < K; k0 += 32) {
        const ushort* Asrc; int kcol, ldA;
        if (k0 < kSplit) { Asrc = A0; kcol = k0;          ldA = kSplit; }
        else             { Asrc = A1; kcol = k0 - kSplit; ldA = K - kSplit; }
        uint4 a0 = *(const uint4*)&Asrc[(size_t)(m0 + rowA) * ldA + kcol + coff];
        uint4 a1 = *(const uint4*)&Asrc[(size_t)(m0 + rowA + 64) * ldA + kcol + coff];
        uint4 b0 = *(const uint4*)&Wt[(size_t)(n0 + rowA) * K + k0 + coff];
        uint4 b1 = *(const uint4*)&Wt[(size_t)(n0 + rowA + 64) * K + k0 + coff];
        __syncthreads();
        *(uint4*)&As[rowA * 40 + coff] = a0;
        *(uint4*)&As[(rowA + 64) * 40 + coff] = a1;
        *(uint4*)&Bs[rowA * 40 + coff] = b0;
        *(uint4*)&Bs[(rowA + 64) * 40 + coff] = b1;
        __syncthreads();
        short8 af[4], bfr[4];
#pragma unroll
        for (int i = 0; i < 4; i++) {
            af[i]  = *(const short8*)&As[(wm * 64 + i * 16 + l16) * 40 + quad * 8];
            bfr[i] = *(const short8*)&Bs[(wn * 64 + i * 16 + l16) * 40 + quad * 8];
        }
#pragma unroll
        for (int i = 0; i < 4; i++)
#pragma unroll
            for (int j = 0; j < 4; j++)
                acc[i][j] = __builtin_amdgcn_mfma_f32_16x16x32_bf16(af[i], bfr[j], acc[i][j], 0, 0, 0);
    }
#pragma unroll
    for (int i = 0; i < 4; i++) {
#pragma unroll
        for (int j = 0; j < 4; j++) {
#pragma unroll
            for (int r = 0; r < 4; r++) {
                float v = acc[i][j][r];
                if (act == 1)      v = v > 0.f ? v + 1.f : __expf(v);
                else if (act == 2) v = fmaxf(v, 0.f);
                long row = m0 + wm * 64 + i * 16 + quad * 4 + r;
                int col = n0 + wn * 64 + j * 16 + l16;
                if (Cf) Cf[row * N + col] = v;
                if (Cb) Cb[row * N + col] = f2b(v);
            }
        }
    }
}

// ---------------- per-class KV / Ksum reduction (SRC-side token lists) --------
__global__ __launch_bounds__(256) void lft_kv_kernel(
    const float* __restrict__ phik, const float* __restrict__ vmat,
    const int* __restrict__ tlist, const int* __restrict__ meta,
    float* kv, float* ksum)
{
    int chunk = blockIdx.x, c = blockIdx.y;
    int b = blockIdx.z >> 3, h = blockIdx.z & 7;
    int off = meta[(b * 8 + c) * 2], n = meta[(b * 8 + c) * 2 + 1];
    int per = (n + KV_NCH - 1) / KV_NCH;
    int s0 = chunk * per;
    int s1 = min(s0 + per, n);
    if (s0 >= s1) return;
    const int* tl = tlist + b * 4800 + off;
    int t = threadIdx.x;
    __shared__ float kb[8][32];
    __shared__ float vb[8][32];
    int od = t >> 3, oe = (t & 7) << 2;
    int lt = t >> 5, ld = t & 31;
    float a0 = 0.f, a1 = 0.f, a2 = 0.f, a3 = 0.f, ak = 0.f;
    for (int s = s0; s < s1; s += 8) {
        float kval = 0.f, vval = 0.f;
        if (s + lt < s1) {
            int tok = tl[s + lt];
            long bse = ((long)b * 4800 + tok) * 256 + h * 32 + ld;
            kval = phik[bse];
            vval = vmat[bse];
        }
        __syncthreads();
        kb[lt][ld] = kval;
        vb[lt][ld] = vval;
        __syncthreads();
#pragma unroll
        for (int j = 0; j < 8; j++) {
            float kd = kb[j][od];
            float4 vv = *(const float4*)&vb[j][oe];
            a0 += kd * vv.x; a1 += kd * vv.y; a2 += kd * vv.z; a3 += kd * vv.w;
            ak += kd;
        }
    }
    float* dst = kv + (((long)(b * NPROTO + c) * 8 + h) << 10) + od * 32 + oe;
    atomicAdd(dst + 0, a0);
    atomicAdd(dst + 1, a1);
    atomicAdd(dst + 2, a2);
    atomicAdd(dst + 3, a3);
    if ((t & 7) == 0)
        atomicAdd(ksum + (((long)(b * NPROTO + c) * 8 + h) << 5) + od, ak);
}

// ---------------- kv fp32 [d][e] + ksum → bf16 B-layout [e'][d], e'<48 -------
// e'=0..31: kv^T ; e'=32: ksum ; e'=33..47: zero
__global__ __launch_bounds__(256) void lft_kvconv_kernel(
    const float* __restrict__ kvb, const float* __restrict__ ksb,
    ushort* __restrict__ kvt)
{
    int bc = blockIdx.x;          // b*8+c
    int t = threadIdx.x;
    int h = t >> 5, d = t & 31;
    const float* kvsrc = kvb + ((long)bc * 8 + h) * 1024;
    const float* kssrc = ksb + ((long)bc * 8 + h) * 32;
    ushort* dst = kvt + ((long)bc * 8 + h) * 1536;
#pragma unroll
    for (int e = 0; e < 32; e++) dst[e * 32 + d] = f2b(kvsrc[d * 32 + e]);
    dst[32 * 32 + d] = f2b(kssrc[d]);
#pragma unroll
    for (int e = 33; e < 48; e++) dst[e * 32 + d] = 0;
}

// ---------------- msg via MFMA over X-SIDE class-sorted lists ----------------
// grid (chunk, c, b); 4 waves, wave handles h = 2*wave, 2*wave+1.
// B-frags (kv slice) in registers; A = phi_q bf16 gather; den = 3rd MFMA tile.
__global__ __launch_bounds__(256) void lft_msg_kernel(
    const ushort* __restrict__ pq, const ushort* __restrict__ kvt,
    const int* __restrict__ tlist, const int* __restrict__ meta,
    ushort* __restrict__ msg)
{
    int chunk = blockIdx.x, c = blockIdx.y, b = blockIdx.z;
    int off = meta[(b * 8 + c) * 2], n = meta[(b * 8 + c) * 2 + 1];
    int per = (n + MSG_NCH - 1) / MSG_NCH;
    int s0 = chunk * per, s1 = min(s0 + per, n);
    if (s0 >= s1) return;
    const int* tl = tlist + b * 4800 + off;
    int t = threadIdx.x;
    int wave = t >> 6, lane = t & 63;
    int l16 = lane & 15, quad = lane >> 4;
    int bc = b * 8 + c;
    short8 bfr[2][3];
#pragma unroll
    for (int hh = 0; hh < 2; hh++) {
        int h = wave * 2 + hh;
        const ushort* kb = kvt + ((long)bc * 8 + h) * 1536;
#pragma unroll
        for (int nt = 0; nt < 3; nt++)
            bfr[hh][nt] = *(const short8*)&kb[(nt * 16 + l16) * 32 + quad * 8];
    }
    for (int s = s0; s < s1; s += 16) {
        int ia = min(s + l16, s1 - 1);
        int tokA = tl[ia];
        long rowA = (long)b * 4800 + tokA;
#pragma unroll
        for (int hh = 0; hh < 2; hh++) {
            int h = wave * 2 + hh;
            short8 a = *(const short8*)&pq[rowA * 256 + h * 32 + quad * 8];
            floatx4 n0 = {}, n1 = {}, dd = {};
            n0 = __builtin_amdgcn_mfma_f32_16x16x32_bf16(a, bfr[hh][0], n0, 0, 0, 0);
            n1 = __builtin_amdgcn_mfma_f32_16x16x32_bf16(a, bfr[hh][1], n1, 0, 0, 0);
            dd = __builtin_amdgcn_mfma_f32_16x16x32_bf16(a, bfr[hh][2], dd, 0, 0, 0);
#pragma unroll
            for (int r = 0; r < 4; r++) {
                int rowi = s + quad * 4 + r;
                float den = __shfl(dd[r], lane & 48, 64);
                float inv = 1.f / (den + 1e-6f);
                int tokr = __shfl(tokA, quad * 4 + r, 64);
                if (rowi < s1) {
                    long base = ((long)b * 4800 + tokr) * 256 + h * 32;
                    msg[base + l16]      = f2b(n0[r] * inv);
                    msg[base + 16 + l16] = f2b(n1[r] * inv);
                }
            }
        }
    }
}

// ---------------- row LayerNorm (256), optional residual+mask, dual outputs ---
__global__ __launch_bounds__(256) void lft_ln_kernel(
    const float* __restrict__ in, float* outF, ushort* outB,
    const float* __restrict__ g, const float* __restrict__ bb,
    const float* resid, const int* __restrict__ cls)
{
    int wave = threadIdx.x >> 6, lane = threadIdx.x & 63;
    long row = (long)blockIdx.x * 4 + wave;
    float4 x = *(const float4*)&in[row * 256 + lane * 4];
    float s = x.x + x.y + x.z + x.w;
#pragma unroll
    for (int o = 32; o >= 1; o >>= 1) s += __shfl_xor(s, o, 64);
    float mean = s * (1.0f / 256.0f);
    float dx = x.x - mean, dy = x.y - mean, dz = x.z - mean, dw = x.w - mean;
    float vs = dx * dx + dy * dy + dz * dz + dw * dw;
#pragma unroll
    for (int o = 32; o >= 1; o >>= 1) vs += __shfl_xor(vs, o, 64);
    float r = rsqrtf(vs * (1.0f / 256.0f) + 1e-5f);
    float4 gv = *(const float4*)&g[lane * 4];
    float4 bv = *(const float4*)&bb[lane * 4];
    float4 y;
    y.x = dx * r * gv.x + bv.x;
    y.y = dy * r * gv.y + bv.y;
    y.z = dz * r * gv.z + bv.z;
    y.w = dw * r * gv.w + bv.w;
    if (resid) {
        float4 xr = *(const float4*)&resid[row * 256 + lane * 4];
        if (cls[row] >= 0) { y.x += xr.x; y.y += xr.y; y.z += xr.z; y.w += xr.w; }
        else y = xr;
    }
    if (outF) *(float4*)&outF[row * 256 + lane * 4] = y;
    if (outB) {
        ushort4 u; u.x = f2b(y.x); u.y = f2b(y.y); u.z = f2b(y.z); u.w = f2b(y.w);
        *(ushort4*)&outB[row * 256 + lane * 4] = u;
    }
}

extern "C" void kernel_launch(void* const* d_in, const int* in_sizes, int n_in,
                              void* d_out, int out_size, void* d_ws, size_t ws_size,
                              hipStream_t stream)
{
    (void)in_sizes; (void)n_in; (void)out_size; (void)ws_size;
    const float* feat0 = (const float*)d_in[0];
    const float* feat1 = (const float*)d_in[1];
    const int*   mask0 = (const int*)d_in[2];
    const int*   mask1 = (const int*)d_in[3];
    const float* f0wo  = (const float*)d_in[4];
    const float* f1wo  = (const float*)d_in[5];
    const float* proto = (const float*)d_in[6];
    const float* Wq = (const float*)d_in[7];
    const float* Wk = (const float*)d_in[8];
    const float* Wv = (const float*)d_in[9];
    const float* Wm = (const float*)d_in[10];
    const float* W1 = (const float*)d_in[11];
    const float* W2 = (const float*)d_in[12];
    const float* g1 = (const float*)d_in[13];
    const float* b1 = (const float*)d_in[14];
    const float* g2 = (const float*)d_in[15];
    const float* b2 = (const float*)d_in[16];
    float* out = (float*)d_out;
    float* ws = (float*)d_ws;

    // ---- workspace layout: total ~245.5 MB ----
    const long FSZ = 9830400L;           // 8*4800*256
    float* fa   = ws;                    // fp32 master feat0 (written layer by layer)
    float* fb   = ws + FSZ;              // fp32 master feat1
    float* kbuf = ws + 2 * FSZ;          // phi_k fp32 ; later Wm out ; later W2 out
    float* vbuf = ws + 3 * FSZ;          // v fp32 ; later reused as hid_bf
    ushort* ub  = (ushort*)(ws + 4 * FSZ);
    ushort* fa_bf  = ub;                 // bf16 shadow of fa
    ushort* fb_bf  = ub + FSZ;           // bf16 shadow of fb
    ushort* msg_bf = ub + 2 * FSZ;       // msg bf16; later LN1 bf16 out
    ushort* qb_bf  = ub + 3 * FSZ;       // phi_q bf16
    ushort* wb     = ub + 4 * FSZ;       // bf16 transposed weights
    ushort* wb1    = wb + 16 * 65536;    // W1^T per layer [512][512]
    ushort* wb2    = wb1 + 4 * 262144;   // W2^T per layer [256][512]
    ushort* kvt    = wb2 + 4 * 131072;   // [64][8][48][32] bf16
    float* kvb = (float*)(kvt + 786432); // [B,NP,H,D,D] = 524288 f
    float* ksb = kvb + 524288;           // [B,NP,H,D]   = 16384 f
    int* cls0 = (int*)(ksb + 16384);
    int* cls1 = cls0 + 38400;
    int* tl0  = cls1 + 38400;            // class-sorted token lists
    int* tl1  = tl0 + 38400;
    int* meta = tl1 + 38400;             // [2][8][8][2] (off,cnt)
    ushort* hid_bf = (ushort*)vbuf;      // [38400,512] bf16 (reuses vbuf after kv)

    // one-time per launch: weights, bf16 casts, classes, class sort
    lft_wconv_kernel<<<dim3(8, 8, 16), 256, 0, stream>>>(Wq, Wk, Wv, Wm, 256, 256, 4, wb);
    lft_wconv_kernel<<<dim3(16, 16, 4), 256, 0, stream>>>(W1, W1, W1, W1, 512, 512, 1, wb1);
    lft_wconv_kernel<<<dim3(16, 8, 4), 256, 0, stream>>>(W2, W2, W2, W2, 512, 256, 1, wb2);
    lft_cast_kernel<<<19200, 256, 0, stream>>>(feat0, feat1, fa_bf, fb_bf);
    hipMemcpyAsync(out + 20352000L, proto, 2048 * 4, hipMemcpyDeviceToDevice, stream);
    lft_class_kernel<<<19200, 256, 0, stream>>>(f0wo, f1wo, mask0, mask1, proto,
                                                out, cls0, cls1);
    lft_sort_kernel<<<16, 256, 0, stream>>>(cls0, cls1, tl0, tl1, meta);

    for (int li = 0; li < 4; li++) {
        const ushort* wq = wb + (size_t)(li * 4 + 0) * 65536;
        const ushort* wk = wb + (size_t)(li * 4 + 1) * 65536;
        const ushort* wv = wb + (size_t)(li * 4 + 2) * 65536;
        const ushort* wm = wb + (size_t)(li * 4 + 3) * 65536;
        const ushort* w1 = wb1 + (size_t)li * 262144;
        const ushort* w2 = wb2 + (size_t)li * 131072;
        const float* g1p = g1 + li * 256; const float* b1p = b1 + li * 256;
        const float* g2p = g2 + li * 256; const float* b2p = b2 + li * 256;

        // tlx/mtx: X-side token list (msg iteration); tls/mts: SRC-side (kv gather)
        auto call = [&](ushort* x_bf, ushort* s_bf, const int* clsx,
                        const int* tlx, const int* mtx,
                        const int* tls, const int* mts,
                        const float* residp, float* outFp) {
            dim3 blk(256);
            dim3 gA(2, 300), gB(4, 300);
            // q = phi(x@Wq) (bf16), k = phi(src@Wk), v = src@Wv
            lft_mfma_gemm<<<gA, blk, 0, stream>>>(x_bf, x_bf, 256, wq, nullptr, qb_bf, 256, 256, 1);
            lft_mfma_gemm<<<gA, blk, 0, stream>>>(s_bf, s_bf, 256, wk, kbuf, nullptr, 256, 256, 1);
            lft_mfma_gemm<<<gA, blk, 0, stream>>>(s_bf, s_bf, 256, wv, vbuf, nullptr, 256, 256, 0);
            hipMemsetAsync(kvb, 0, (524288 + 16384) * 4, stream);
            lft_kv_kernel<<<dim3(KV_NCH, 8, 64), blk, 0, stream>>>(kbuf, vbuf, tls, mts, kvb, ksb);
            lft_kvconv_kernel<<<64, blk, 0, stream>>>(kvb, ksb, kvt);
            lft_msg_kernel<<<dim3(MSG_NCH, 8, 8), blk, 0, stream>>>(qb_bf, kvt, tlx, mtx, msg_bf);
            // msg = LN(msg @ Wm)*g1+b1  (LN out bf16 only, reuses msg_bf)
            lft_mfma_gemm<<<gA, blk, 0, stream>>>(msg_bf, msg_bf, 256, wm, kbuf, nullptr, 256, 256, 0);
            lft_ln_kernel<<<9600, blk, 0, stream>>>(kbuf, nullptr, msg_bf, g1p, b1p, nullptr, nullptr);
            // hid = relu([x|msg]@W1) (bf16) ; m = hid@W2 → kbuf ; out = valid ? resid+LN(m) : resid
            lft_mfma_gemm<<<gB, blk, 0, stream>>>(x_bf, msg_bf, 256, w1, nullptr, hid_bf, 512, 512, 2);
            lft_mfma_gemm<<<gA, blk, 0, stream>>>(hid_bf, hid_bf, 512, w2, kbuf, nullptr, 256, 512, 0);
            lft_ln_kernel<<<9600, blk, 0, stream>>>(kbuf, outFp, x_bf, g2p, b2p, residp, clsx);
        };

        const float* ra = (li == 0) ? feat0 : fa;
        const float* rb = (li == 0) ? feat1 : fb;
        float* oa = (li == 3) ? out : fa;
        float* ob = (li == 3) ? (out + FSZ) : fb;

        if ((li & 1) == 0) {           // self-self
            call(fa_bf, fa_bf, cls0, tl0, meta,       tl0, meta,       ra, oa);
            call(fb_bf, fb_bf, cls1, tl1, meta + 128, tl1, meta + 128, rb, ob);
        } else {                       // cross-self: x=feat0 iterates tl0, gathers tl1
            call(fa_bf, fb_bf, cls0, tl0, meta,       tl1, meta + 128, ra, oa);
            call(fb_bf, fa_bf, cls1, tl1, meta + 128, tl0, meta,       rb, ob);
        }
    }
}